// Round 7
// baseline (600.758 us; speedup 1.0000x reference)
//
#include <hip/hip_runtime.h>
#include <hip/hip_fp16.h>
#include <math.h>

#define N_NODES 100000
#define N_EDGES 1600000
#define F_IN 15
#define MASK40 ((1ull << 40) - 1)

// bucketed counting-sort CSR build: buckets of 512 nodes (dst>>9)
#define NBLK1 256                           // edge-partition blocks for hist/scatter
#define EPB   (N_EDGES / NBLK1)             // 6250 edges per block (exact)
#define NBUCK 256                           // allocated buckets; used = 196
#define NBUCK_USED ((N_NODES + 511) >> 9)   // 196

typedef _Float16 half8 __attribute__((ext_vector_type(8)));
typedef float f32x4 __attribute__((ext_vector_type(4)));

// ---------------- prelude: sort-based CSR build (no global atomics) ----------

// per-block 256-bin histogram of dst>>9 in LDS; hist[bin*NBLK1 + blk]
__global__ __launch_bounds__(1024) void k_hist(const int* __restrict__ dst,
                                               int* __restrict__ hist) {
    __shared__ int bins[NBUCK];
    int t = threadIdx.x, blk = blockIdx.x;
    if (t < NBUCK) bins[t] = 0;
    __syncthreads();
    int e0 = blk * EPB;
    for (int e = e0 + t; e < e0 + EPB; e += 1024)
        atomicAdd(&bins[dst[e] >> 9], 1);
    __syncthreads();
    if (t < NBUCK) hist[t * NBLK1 + blk] = bins[t];
}

// single-block exclusive scan of hist[65536] in place; also bucketBase[b] =
// scan value at b*NBLK1, bucketBase[NBUCK]=E, rowptr[N]=E.
__global__ __launch_bounds__(1024) void k_scan(int* __restrict__ hist,
                                               int* __restrict__ bucketBase,
                                               int* __restrict__ rowptr) {
    __shared__ int sc[1024];
    int t = threadIdx.x;
    int base = t * 64;
    int vals[64];
    int tot = 0;
#pragma unroll
    for (int k = 0; k < 64; k++) { vals[k] = hist[base + k]; tot += vals[k]; }
    sc[t] = tot;
    __syncthreads();
    for (int off = 1; off < 1024; off <<= 1) {
        int u = (t >= off) ? sc[t - off] : 0;
        __syncthreads();
        sc[t] += u;
        __syncthreads();
    }
    int run = sc[t] - tot;  // exclusive base of this thread's segment
#pragma unroll
    for (int k = 0; k < 64; k++) {
        int idx = base + k;
        if ((idx & (NBLK1 - 1)) == 0) bucketBase[idx / NBLK1] = run;
        int v = vals[k];
        hist[idx] = run;
        run += v;
    }
    if (t == 0) { bucketBase[NBUCK] = N_EDGES; rowptr[N_NODES] = N_EDGES; }
}

// scatter edges into bucket-contiguous record array via LDS cursors.
// record: x = src | (dst&511)<<17  (src<2^17, 9-bit dstlo), y = bits(w)
__global__ __launch_bounds__(1024) void k_scatter(const int* __restrict__ src,
        const int* __restrict__ dst, const float* __restrict__ w,
        const int* __restrict__ hist, int2* __restrict__ brec) {
    __shared__ int cursor[NBUCK];
    int t = threadIdx.x, blk = blockIdx.x;
    if (t < NBUCK) cursor[t] = hist[t * NBLK1 + blk];
    __syncthreads();
    int e0 = blk * EPB;
    for (int e = e0 + t; e < e0 + EPB; e += 1024) {
        int d = dst[e];
        int pos = atomicAdd(&cursor[d >> 9], 1);
        brec[pos] = make_int2(src[e] | ((d & 511) << 17), __float_as_int(w[e]));
    }
}

// per-bucket: packed count/weight-sum per node in LDS (same 24.40 packing as
// the old k_cnt -> identical deg numerics), then dinv + rowptr via LDS scan.
__global__ __launch_bounds__(512) void k_deg(const int2* __restrict__ brec,
        const int* __restrict__ bucketBase, float* __restrict__ dinv,
        int* __restrict__ rowptr) {
    __shared__ unsigned long long packedl[512];
    __shared__ int sc[512];
    int t = threadIdx.x, b = blockIdx.x;
    packedl[t] = 0ull;
    __syncthreads();
    int ebase = bucketBase[b], eend = bucketBase[b + 1];
    for (int e = ebase + t; e < eend; e += 512) {
        int2 r = brec[e];
        int dlo = (r.x >> 17) & 511;
        float wv = __int_as_float(r.y);
        unsigned long long contrib =
            (1ull << 40) + (unsigned long long)((double)wv * 4294967296.0);
        atomicAdd(&packedl[dlo], contrib);
    }
    __syncthreads();
    unsigned long long p = packedl[t];
    int cnt = (int)(p >> 40);
    int n = (b << 9) + t;
    if (n < N_NODES) {
        float deg = 1.0f + (float)((double)(p & MASK40) * 0x1p-32);
        dinv[n] = rsqrtf(deg);
    }
    sc[t] = cnt;
    __syncthreads();
    for (int off = 1; off < 512; off <<= 1) {
        int u = (t >= off) ? sc[t - off] : 0;
        __syncthreads();
        sc[t] += u;
        __syncthreads();
    }
    if (n < N_NODES) rowptr[n] = ebase + sc[t] - cnt;  // exclusive prefix
}

// per-bucket final CSR fill: LDS cursors seeded from rowptr; nm in fp32 with
// the exact formula the old k_fill used.
__global__ __launch_bounds__(512) void k_csr(const int2* __restrict__ brec,
        const int* __restrict__ bucketBase, const int* __restrict__ rowptr,
        const float* __restrict__ dinv, int2* __restrict__ csr) {
    __shared__ int cursor[512];
    __shared__ float dl[512];
    int t = threadIdx.x, b = blockIdx.x;
    int n = (b << 9) + t;
    if (n < N_NODES) { cursor[t] = rowptr[n]; dl[t] = dinv[n]; }
    else             { cursor[t] = 0;         dl[t] = 0.f; }
    __syncthreads();
    int ebase = bucketBase[b], eend = bucketBase[b + 1];
    for (int e = ebase + t; e < eend; e += 512) {
        int2 r = brec[e];
        int dlo = (r.x >> 17) & 511;
        int s = r.x & 0x1FFFF;
        float wv = __int_as_float(r.y);
        int slot = atomicAdd(&cursor[dlo], 1);
        float nm = dinv[s] * wv * dl[dlo];
        csr[slot] = make_int2(s, __float_as_int(nm));
    }
}

// ---------------- layer 0 dense transform: [N,15]@[15,64] -> fp16 (no relu) ----

__global__ void k_gemm0(const float* __restrict__ x, const float* __restrict__ W,
                        __half* __restrict__ out) {
    __shared__ float Ws[F_IN * 64];
    int t = threadIdx.x;
    for (int i = t; i < F_IN * 64; i += 256) Ws[i] = W[i];
    __syncthreads();
    int r = blockIdx.x * 4 + (t >> 6);
    int c = t & 63;
    if (r < N_NODES) {
        const float* xr = x + r * F_IN;      // int index: < 1.5M
        float acc = 0.f;
#pragma unroll
        for (int k = 0; k < F_IN; k++) acc += xr[k] * Ws[k * 64 + c];
        out[r * 64 + c] = __float2half(acc); // int index: < 6.4M
    }
}

// ---------------- fused aggregation + MFMA dense epilogue ----------------
// Wave = 12 nodes; lane = (sub: which edge of a pair) x (fl: feature pair).
// NPB=48 -> grid 2084 blocks ~= the 2048-block residency capacity at 8
// blocks/CU, eliminating the 1.5-generation drain that capped occupancy at
// 56% with the old 3125-block grid. Edge records staged in LDS; fma_mix
// accumulate; outputs staged in a dedicated LDS region and stored as full
// 128 B rows.

#define SE_CAP 128          // staged edges per wave (chunked if exceeded)
#define G_STRIDE 72         // halves; 144 B rows keep half8 loads 16B-aligned
#define NPB 48              // nodes per block
#define NPW 12              // nodes per wave
#define GG ((N_NODES + NPB - 1) / NPB)   // 2084

template <bool WEP, bool SIG>
__global__ __launch_bounds__(256, 8) void k_gather4(
        const int* __restrict__ rowptr, const int2* __restrict__ csr,
        const __half* __restrict__ hin, const float* __restrict__ dinv,
        const float* __restrict__ W, const float* __restrict__ b,
        void* __restrict__ outp) {
    extern __shared__ char smem[];
    int t = threadIdx.x, wv = t >> 6, lane = t & 63;
    int sub = lane >> 5, fl = lane & 31;
    int2* se = (int2*)smem + wv * SE_CAP;                 // 4 x 1 KB
    _Float16* G = (_Float16*)(smem + 4 * SE_CAP * 8);     // [48][G_STRIDE]
    char* stg = smem + 4 * SE_CAP * 8 + NPB * G_STRIDE * 2;  // output staging

    int nb = blockIdx.x * NPB;
    int n0w = nb + wv * NPW;

    int rp[NPW + 1];
#pragma unroll
    for (int j = 0; j <= NPW; j++) {
        int idx = n0w + j;
        rp[j] = rowptr[idx < N_NODES ? idx : N_NODES];
    }
    int base = rp[0], end = rp[NPW];

    const __half2* h2 = (const __half2*)hin;  // row stride = 32 half2

    // self-loop init: acc[j] = dinv^2 * h (h already activated by producer)
    float2 acc[NPW];
#pragma unroll
    for (int j = 0; j < NPW; j++) {
        int n = n0w + j;
        bool valid = n < N_NODES;
        float dv = valid ? dinv[n] : 0.f;
        int nc = valid ? n : 0;
        __half2 hq = h2[nc * 32 + fl];
        float w0 = (sub == 0) ? dv * dv : 0.f;
        acc[j].x = w0 * __low2float(hq);
        acc[j].y = w0 * __high2float(hq);
    }

    for (int cb = base; cb < end; cb += SE_CAP) {
        int ce = cb + SE_CAP; if (ce > end) ce = end;
        int cn = ce - cb;
        for (int i = lane; i < cn; i += 64) se[i] = csr[cb + i];
        __builtin_amdgcn_wave_barrier();
#pragma unroll
        for (int j = 0; j < NPW; j++) {
            int lo = rp[j] < cb ? cb : rp[j];
            int hi = rp[j + 1] > ce ? ce : rp[j + 1];
            int i = lo - cb, iend = hi - cb;
            // 4 pairs (8 edges) per iteration
            for (; i + 7 < iend; i += 8) {
                int2 r0 = se[i + sub],     r1 = se[i + 2 + sub];
                int2 r2 = se[i + 4 + sub], r3 = se[i + 6 + sub];
                __half2 q0 = h2[r0.x * 32 + fl];
                __half2 q1 = h2[r1.x * 32 + fl];
                __half2 q2 = h2[r2.x * 32 + fl];
                __half2 q3 = h2[r3.x * 32 + fl];
                float n0 = __int_as_float(r0.y), n1 = __int_as_float(r1.y);
                float n2 = __int_as_float(r2.y), n3 = __int_as_float(r3.y);
                acc[j].x = fmaf(n0, __low2float(q0), acc[j].x);
                acc[j].y = fmaf(n0, __high2float(q0), acc[j].y);
                acc[j].x = fmaf(n1, __low2float(q1), acc[j].x);
                acc[j].y = fmaf(n1, __high2float(q1), acc[j].y);
                acc[j].x = fmaf(n2, __low2float(q2), acc[j].x);
                acc[j].y = fmaf(n2, __high2float(q2), acc[j].y);
                acc[j].x = fmaf(n3, __low2float(q3), acc[j].x);
                acc[j].y = fmaf(n3, __high2float(q3), acc[j].y);
            }
            for (; i + 1 < iend; i += 2) {
                int2 r = se[i + sub];
                __half2 q = h2[r.x * 32 + fl];
                float nm = __int_as_float(r.y);
                acc[j].x = fmaf(nm, __low2float(q), acc[j].x);
                acc[j].y = fmaf(nm, __high2float(q), acc[j].y);
            }
            if (i < iend) {  // odd tail: sub0 only
                int2 r = se[i];
                __half2 q = h2[r.x * 32 + fl];
                float nm = (sub == 0) ? __int_as_float(r.y) : 0.f;
                acc[j].x = fmaf(nm, __low2float(q), acc[j].x);
                acc[j].y = fmaf(nm, __high2float(q), acc[j].y);
            }
        }
        __builtin_amdgcn_wave_barrier();
    }

    // combine sub-halves: feature pair fl lives in lanes fl and fl+32
#pragma unroll
    for (int j = 0; j < NPW; j++) {
        acc[j].x += __shfl_xor(acc[j].x, 32);
        acc[j].y += __shfl_xor(acc[j].y, 32);
    }

    if (!WEP) {
        // layer 0: out = relu(g + b) fp16, written as half2 by sub0 lanes
        float2 bv = ((const float2*)b)[fl];
        if (sub == 0) {
#pragma unroll
            for (int j = 0; j < NPW; j++) {
                int n = n0w + j;
                if (n < N_NODES) {
                    float ox = fmaxf(acc[j].x + bv.x, 0.f);
                    float oy = fmaxf(acc[j].y + bv.y, 0.f);
                    ((__half2*)outp)[n * 32 + fl] = __floats2half2_rn(ox, oy);
                }
            }
        }
        return;
    }

    // write G rows (fp16) from sub0 lanes
    if (sub == 0) {
        __half2* G2 = (__half2*)G;
#pragma unroll
        for (int j = 0; j < NPW; j++)
            G2[(wv * NPW + j) * (G_STRIDE / 2) + fl] = __floats2half2_rn(acc[j].x, acc[j].y);
    }
    __syncthreads();

    // ---- MFMA epilogue: O[48x64] = G @ (W_hi + W_lo) + b ----
    // Each wave owns one 16-col strip (nc0 = wv*16) across 3 row-bands.
    int col = lane & 15, quad = lane >> 4;
    int nc0 = wv * 16;

    half8 bf[2][2];  // [kt][hi/lo]
#pragma unroll
    for (int kt = 0; kt < 2; kt++) {
#pragma unroll
        for (int j = 0; j < 8; j++) {
            float w = W[(kt * 32 + quad * 8 + j) * 64 + nc0 + col];
            _Float16 hi = (_Float16)w;
            bf[kt][0][j] = hi;
            bf[kt][1][j] = (_Float16)(w - (float)hi);
        }
    }
    float b0v = b[nc0 + col];

#pragma unroll
    for (int band = 0; band < 3; band++) {
        half8 a0 = *(const half8*)&G[(band * 16 + col) * G_STRIDE + 0 * 32 + quad * 8];
        half8 a1 = *(const half8*)&G[(band * 16 + col) * G_STRIDE + 1 * 32 + quad * 8];
        f32x4 c = (f32x4){b0v, b0v, b0v, b0v};
        c = __builtin_amdgcn_mfma_f32_16x16x32_f16(a0, bf[0][0], c, 0, 0, 0);
        c = __builtin_amdgcn_mfma_f32_16x16x32_f16(a0, bf[0][1], c, 0, 0, 0);
        c = __builtin_amdgcn_mfma_f32_16x16x32_f16(a1, bf[1][0], c, 0, 0, 0);
        c = __builtin_amdgcn_mfma_f32_16x16x32_f16(a1, bf[1][1], c, 0, 0, 0);

        // C/D layout: col = lane&15, row = quad*4 + reg. Stage to LDS.
        if (!SIG) {
            _Float16* S = (_Float16*)stg;   // [48][G_STRIDE]
#pragma unroll
            for (int r = 0; r < 4; r++)
                S[(band * 16 + quad * 4 + r) * G_STRIDE + nc0 + col] =
                    (_Float16)fmaxf(c[r], 0.f);   // relu at producer
        } else {
            float* S = (float*)stg;         // [48][68]
#pragma unroll
            for (int r = 0; r < 4; r++)
                S[(band * 16 + quad * 4 + r) * 68 + nc0 + col] =
                    1.0f / (1.0f + expf(-c[r]));
        }
    }
    __syncthreads();

    // coalesced store-out of full rows
    if (!SIG) {
        const _Float16* S = (const _Float16*)stg;
        // 48 rows x 8 half8-segments = 384 units, 256 threads
#pragma unroll
        for (int k = 0; k < 2; k++) {
            int lin = t + k * 256;
            if (lin < 48 * 8) {
                int row = lin >> 3, seg = lin & 7;
                if (nb + row < N_NODES) {
                    half8 v = *(const half8*)&S[row * G_STRIDE + seg * 8];
                    *(half8*)((__half*)outp + (nb + row) * 64 + seg * 8) = v;
                }
            }
        }
    } else {
        const float* S = (const float*)stg;
        // 48 rows x 16 float4-segments = 768 units, 256 threads
#pragma unroll
        for (int k = 0; k < 3; k++) {
            int lin = t + k * 256;
            int row = lin >> 4, seg = lin & 15;
            if (nb + row < N_NODES) {
                float4 v = *(const float4*)&S[row * 68 + seg * 4];
                *(float4*)((float*)outp + (nb + row) * 64 + seg * 4) = v;
            }
        }
    }
}

// ---------------- launch ----------------

extern "C" void kernel_launch(void* const* d_in, const int* in_sizes, int n_in,
                              void* d_out, int out_size, void* d_ws, size_t ws_size,
                              hipStream_t stream) {
    const float* x  = (const float*)d_in[0];
    const int*   ei = (const int*)  d_in[1];
    const float* ew = (const float*)d_in[2];
    const float* W0 = (const float*)d_in[3];
    const float* b0 = (const float*)d_in[4];
    const float* Wm = (const float*)d_in[5];
    const float* bm = (const float*)d_in[6];
    const float* Wl = (const float*)d_in[7];
    const float* bl = (const float*)d_in[8];
    float* out = (float*)d_out;

    const int* src = ei;
    const int* dst = ei + N_EDGES;

    char* ws = (char*)d_ws;
    int*    hist   = (int*)  (ws + 0);                // 256 KB (NBUCK*NBLK1*4)
    int*    bbase  = (int*)  (ws + (1u << 18));       // ~1 KB (NBUCK+1 ints)
    float*  dinv   = (float*)(ws + (1u << 20));       // 400 KB
    int*    rowptr = (int*)  (ws + (2u << 20));       // 400 KB + 4
    int2*   brec   = (int2*) (ws + (3u << 20));       // 12.8 MB
    int2*   csr    = (int2*) (ws + (16u << 20));      // 12.8 MB
    __half* htmp   = (__half*)(ws + (29u << 20));     // 12.8 MB
    __half* hA     = (__half*)(ws + (42u << 20));     // 12.8 MB
    __half* hB     = (__half*)(ws + (55u << 20));     // 12.8 MB

    int gR4 = (N_NODES + 3) / 4;              // 25000 (gemm0)

    const size_t smem0 = 4 * SE_CAP * 8;                                  // 4 KB
    const size_t smemM = 4 * SE_CAP * 8 + NPB * G_STRIDE * 2 * 2;         // 17.9 KB
    const size_t smemS = 4 * SE_CAP * 8 + NPB * G_STRIDE * 2 + NPB * 68 * 4; // 24 KB

    // prelude: bucketed counting sort (LDS atomics only), then per-bucket
    // degree/rowptr and final CSR fill
    hipLaunchKernelGGL(k_hist,    dim3(NBLK1), dim3(1024), 0, stream, dst, hist);
    hipLaunchKernelGGL(k_scan,    dim3(1),     dim3(1024), 0, stream, hist, bbase, rowptr);
    hipLaunchKernelGGL(k_scatter, dim3(NBLK1), dim3(1024), 0, stream, src, dst, ew, hist, brec);
    hipLaunchKernelGGL(k_deg,     dim3(NBUCK_USED), dim3(512), 0, stream, brec, bbase, dinv, rowptr);
    hipLaunchKernelGGL(k_csr,     dim3(NBUCK_USED), dim3(512), 0, stream, brec, bbase, rowptr, dinv, csr);

    // layer 0: x W0 -> fp16 (pre-act), then aggregate +b0, relu at store -> hA
    hipLaunchKernelGGL(k_gemm0,   dim3(gR4), dim3(256), 0, stream, x, W0, htmp);
    hipLaunchKernelGGL((k_gather4<false, false>), dim3(GG), dim3(256), smem0, stream,
                       rowptr, csr, htmp, dinv, (const float*)nullptr, b0, (void*)hA);

    // middle layers 1..6: fused (A h) W + b via MFMA, relu at store, fp16 -> fp16
    __half* hin = hA;
    __half* hout = hB;
    for (int i = 0; i < 6; i++) {
        const float* Wi = Wm + (long)i * 64 * 64;
        const float* bi = bm + (long)i * 64;
        hipLaunchKernelGGL((k_gather4<true, false>), dim3(GG), dim3(256), smemM, stream,
                           rowptr, csr, hin, dinv, Wi, bi, (void*)hout);
        __half* t2 = hin; hin = hout; hout = t2;
    }

    // final layer: fused aggregate + W + bias + sigmoid -> fp32 d_out
    hipLaunchKernelGGL((k_gather4<true, true>), dim3(GG), dim3(256), smemS, stream,
                       rowptr, csr, hin, dinv, Wl, bl, (void*)out);
}

// Round 8
// 520.465 us; speedup vs baseline: 1.1543x; 1.1543x over previous
//
#include <hip/hip_runtime.h>
#include <hip/hip_fp16.h>
#include <math.h>

#define N_NODES 100000
#define N_EDGES 1600000
#define F_IN 15
#define MASK40 ((1ull << 40) - 1)

// bucketed counting-sort CSR build: buckets of 512 nodes (dst>>9)
#define NBLK1 256                           // edge-partition blocks for hist/scatter
#define EPB   (N_EDGES / NBLK1)             // 6250 edges per block (exact)
#define NBUCK 256                           // allocated buckets; used = 196
#define NBUCK_USED ((N_NODES + 511) >> 9)   // 196

typedef _Float16 half8 __attribute__((ext_vector_type(8)));
typedef float f32x4 __attribute__((ext_vector_type(4)));

// ---------------- prelude: sort-based CSR build (no global atomics) ----------

// per-block 256-bin histogram of dst>>9 in LDS; hist[bin*NBLK1 + blk]
__global__ __launch_bounds__(1024) void k_hist(const int* __restrict__ dst,
                                               int* __restrict__ hist) {
    __shared__ int bins[NBUCK];
    int t = threadIdx.x, blk = blockIdx.x;
    if (t < NBUCK) bins[t] = 0;
    __syncthreads();
    int e0 = blk * EPB;
    for (int e = e0 + t; e < e0 + EPB; e += 1024)
        atomicAdd(&bins[dst[e] >> 9], 1);
    __syncthreads();
    if (t < NBUCK) hist[t * NBLK1 + blk] = bins[t];
}

// single-block exclusive scan of hist[65536] in place; also bucketBase[b] =
// scan value at b*NBLK1, bucketBase[NBUCK]=E, rowptr[N]=E.
__global__ __launch_bounds__(1024) void k_scan(int* __restrict__ hist,
                                               int* __restrict__ bucketBase,
                                               int* __restrict__ rowptr) {
    __shared__ int sc[1024];
    int t = threadIdx.x;
    int base = t * 64;
    int vals[64];
    int tot = 0;
#pragma unroll
    for (int k = 0; k < 64; k++) { vals[k] = hist[base + k]; tot += vals[k]; }
    sc[t] = tot;
    __syncthreads();
    for (int off = 1; off < 1024; off <<= 1) {
        int u = (t >= off) ? sc[t - off] : 0;
        __syncthreads();
        sc[t] += u;
        __syncthreads();
    }
    int run = sc[t] - tot;  // exclusive base of this thread's segment
#pragma unroll
    for (int k = 0; k < 64; k++) {
        int idx = base + k;
        if ((idx & (NBLK1 - 1)) == 0) bucketBase[idx / NBLK1] = run;
        int v = vals[k];
        hist[idx] = run;
        run += v;
    }
    if (t == 0) { bucketBase[NBUCK] = N_EDGES; rowptr[N_NODES] = N_EDGES; }
}

// scatter edges into bucket-contiguous record array via LDS cursors.
// record: x = src | (dst&511)<<17  (src<2^17, 9-bit dstlo), y = bits(w)
__global__ __launch_bounds__(1024) void k_scatter(const int* __restrict__ src,
        const int* __restrict__ dst, const float* __restrict__ w,
        const int* __restrict__ hist, int2* __restrict__ brec) {
    __shared__ int cursor[NBUCK];
    int t = threadIdx.x, blk = blockIdx.x;
    if (t < NBUCK) cursor[t] = hist[t * NBLK1 + blk];
    __syncthreads();
    int e0 = blk * EPB;
    for (int e = e0 + t; e < e0 + EPB; e += 1024) {
        int d = dst[e];
        int pos = atomicAdd(&cursor[d >> 9], 1);
        brec[pos] = make_int2(src[e] | ((d & 511) << 17), __float_as_int(w[e]));
    }
}

// per-bucket: packed count/weight-sum per node in LDS (same 24.40 packing as
// the old k_cnt -> identical deg numerics), then dinv + rowptr via LDS scan.
__global__ __launch_bounds__(512) void k_deg(const int2* __restrict__ brec,
        const int* __restrict__ bucketBase, float* __restrict__ dinv,
        int* __restrict__ rowptr) {
    __shared__ unsigned long long packedl[512];
    __shared__ int sc[512];
    int t = threadIdx.x, b = blockIdx.x;
    packedl[t] = 0ull;
    __syncthreads();
    int ebase = bucketBase[b], eend = bucketBase[b + 1];
    for (int e = ebase + t; e < eend; e += 512) {
        int2 r = brec[e];
        int dlo = (r.x >> 17) & 511;
        float wv = __int_as_float(r.y);
        unsigned long long contrib =
            (1ull << 40) + (unsigned long long)((double)wv * 4294967296.0);
        atomicAdd(&packedl[dlo], contrib);
    }
    __syncthreads();
    unsigned long long p = packedl[t];
    int cnt = (int)(p >> 40);
    int n = (b << 9) + t;
    if (n < N_NODES) {
        float deg = 1.0f + (float)((double)(p & MASK40) * 0x1p-32);
        dinv[n] = rsqrtf(deg);
    }
    sc[t] = cnt;
    __syncthreads();
    for (int off = 1; off < 512; off <<= 1) {
        int u = (t >= off) ? sc[t - off] : 0;
        __syncthreads();
        sc[t] += u;
        __syncthreads();
    }
    if (n < N_NODES) rowptr[n] = ebase + sc[t] - cnt;  // exclusive prefix
}

// per-bucket final CSR fill: LDS cursors seeded from rowptr; nm in fp32 with
// the exact formula the old k_fill used.
__global__ __launch_bounds__(512) void k_csr(const int2* __restrict__ brec,
        const int* __restrict__ bucketBase, const int* __restrict__ rowptr,
        const float* __restrict__ dinv, int2* __restrict__ csr) {
    __shared__ int cursor[512];
    __shared__ float dl[512];
    int t = threadIdx.x, b = blockIdx.x;
    int n = (b << 9) + t;
    if (n < N_NODES) { cursor[t] = rowptr[n]; dl[t] = dinv[n]; }
    else             { cursor[t] = 0;         dl[t] = 0.f; }
    __syncthreads();
    int ebase = bucketBase[b], eend = bucketBase[b + 1];
    for (int e = ebase + t; e < eend; e += 512) {
        int2 r = brec[e];
        int dlo = (r.x >> 17) & 511;
        int s = r.x & 0x1FFFF;
        float wv = __int_as_float(r.y);
        int slot = atomicAdd(&cursor[dlo], 1);
        float nm = dinv[s] * wv * dl[dlo];
        csr[slot] = make_int2(s, __float_as_int(nm));
    }
}

// ---------------- layer 0 dense transform: [N,15]@[15,64] -> fp16 (no relu) ----

__global__ void k_gemm0(const float* __restrict__ x, const float* __restrict__ W,
                        __half* __restrict__ out) {
    __shared__ float Ws[F_IN * 64];
    int t = threadIdx.x;
    for (int i = t; i < F_IN * 64; i += 256) Ws[i] = W[i];
    __syncthreads();
    int r = blockIdx.x * 4 + (t >> 6);
    int c = t & 63;
    if (r < N_NODES) {
        const float* xr = x + r * F_IN;      // int index: < 1.5M
        float acc = 0.f;
#pragma unroll
        for (int k = 0; k < F_IN; k++) acc += xr[k] * Ws[k * 64 + c];
        out[r * 64 + c] = __float2half(acc); // int index: < 6.4M
    }
}

// ---------------- fused aggregation + MFMA dense epilogue ----------------
// Wave = 8 nodes; lane = (sub: which edge of a pair) x (fl: feature pair).
// Edge records staged in LDS; accumulate via fma_mix (f16 operand folded into
// f32 FMA, no separate cvt). 16-edge (8-pair) unroll doubles in-flight gather
// loads per wave (4 -> 8) to cover L2/HBM latency. All hot indices 32-bit.
// Outputs staged in LDS and stored as full 128 B rows (half8 / float4).

#define SE_CAP 128          // staged edges per wave (chunked if exceeded)
#define G_STRIDE 72         // halves; 144 B rows keep half8 loads 16B-aligned

template <bool WEP, bool SIG>
__global__ __launch_bounds__(256, 8) void k_gather4(
        const int* __restrict__ rowptr, const int2* __restrict__ csr,
        const __half* __restrict__ hin, const float* __restrict__ dinv,
        const float* __restrict__ W, const float* __restrict__ b,
        void* __restrict__ outp) {
    extern __shared__ char smem[];
    int t = threadIdx.x, wv = t >> 6, lane = t & 63;
    int sub = lane >> 5, fl = lane & 31;
    int2* se = (int2*)smem + wv * SE_CAP;                 // 4 x 1 KB
    _Float16* G = (_Float16*)(smem + 4 * SE_CAP * 8);     // [32][G_STRIDE]

    int nb = blockIdx.x * 32;      // grid exact: 3125*32 = 100000
    int n0w = nb + wv * 8;

    int rp[9];
#pragma unroll
    for (int j = 0; j < 9; j++) rp[j] = rowptr[n0w + j];
    int base = rp[0], end = rp[8];

    const __half2* h2 = (const __half2*)hin;  // row stride = 32 half2

    // self-loop init: acc[j] = dinv^2 * h (h already activated by producer)
    float2 acc[8];
#pragma unroll
    for (int j = 0; j < 8; j++) {
        int n = n0w + j;
        float dv = dinv[n];
        __half2 hq = h2[n * 32 + fl];
        float w0 = (sub == 0) ? dv * dv : 0.f;
        acc[j].x = w0 * __low2float(hq);
        acc[j].y = w0 * __high2float(hq);
    }

    for (int cb = base; cb < end; cb += SE_CAP) {
        int ce = cb + SE_CAP; if (ce > end) ce = end;
        int cn = ce - cb;
        for (int i = lane; i < cn; i += 64) se[i] = csr[cb + i];
        __builtin_amdgcn_wave_barrier();
#pragma unroll
        for (int j = 0; j < 8; j++) {
            int lo = rp[j] < cb ? cb : rp[j];
            int hi = rp[j + 1] > ce ? ce : rp[j + 1];
            int i = lo - cb, iend = hi - cb;
            // 8 pairs (16 edges) per iteration: 8 loads in flight
            for (; i + 15 < iend; i += 16) {
                int2 r0 = se[i + sub],      r1 = se[i + 2 + sub];
                int2 r2 = se[i + 4 + sub],  r3 = se[i + 6 + sub];
                int2 r4 = se[i + 8 + sub],  r5 = se[i + 10 + sub];
                int2 r6 = se[i + 12 + sub], r7 = se[i + 14 + sub];
                __half2 q0 = h2[r0.x * 32 + fl];
                __half2 q1 = h2[r1.x * 32 + fl];
                __half2 q2 = h2[r2.x * 32 + fl];
                __half2 q3 = h2[r3.x * 32 + fl];
                __half2 q4 = h2[r4.x * 32 + fl];
                __half2 q5 = h2[r5.x * 32 + fl];
                __half2 q6 = h2[r6.x * 32 + fl];
                __half2 q7 = h2[r7.x * 32 + fl];
                float n0 = __int_as_float(r0.y), n1 = __int_as_float(r1.y);
                float n2 = __int_as_float(r2.y), n3 = __int_as_float(r3.y);
                float n4 = __int_as_float(r4.y), n5 = __int_as_float(r5.y);
                float n6 = __int_as_float(r6.y), n7 = __int_as_float(r7.y);
                acc[j].x = fmaf(n0, __low2float(q0), acc[j].x);
                acc[j].y = fmaf(n0, __high2float(q0), acc[j].y);
                acc[j].x = fmaf(n1, __low2float(q1), acc[j].x);
                acc[j].y = fmaf(n1, __high2float(q1), acc[j].y);
                acc[j].x = fmaf(n2, __low2float(q2), acc[j].x);
                acc[j].y = fmaf(n2, __high2float(q2), acc[j].y);
                acc[j].x = fmaf(n3, __low2float(q3), acc[j].x);
                acc[j].y = fmaf(n3, __high2float(q3), acc[j].y);
                acc[j].x = fmaf(n4, __low2float(q4), acc[j].x);
                acc[j].y = fmaf(n4, __high2float(q4), acc[j].y);
                acc[j].x = fmaf(n5, __low2float(q5), acc[j].x);
                acc[j].y = fmaf(n5, __high2float(q5), acc[j].y);
                acc[j].x = fmaf(n6, __low2float(q6), acc[j].x);
                acc[j].y = fmaf(n6, __high2float(q6), acc[j].y);
                acc[j].x = fmaf(n7, __low2float(q7), acc[j].x);
                acc[j].y = fmaf(n7, __high2float(q7), acc[j].y);
            }
            // 4 pairs (8 edges)
            for (; i + 7 < iend; i += 8) {
                int2 r0 = se[i + sub],     r1 = se[i + 2 + sub];
                int2 r2 = se[i + 4 + sub], r3 = se[i + 6 + sub];
                __half2 q0 = h2[r0.x * 32 + fl];
                __half2 q1 = h2[r1.x * 32 + fl];
                __half2 q2 = h2[r2.x * 32 + fl];
                __half2 q3 = h2[r3.x * 32 + fl];
                float n0 = __int_as_float(r0.y), n1 = __int_as_float(r1.y);
                float n2 = __int_as_float(r2.y), n3 = __int_as_float(r3.y);
                acc[j].x = fmaf(n0, __low2float(q0), acc[j].x);
                acc[j].y = fmaf(n0, __high2float(q0), acc[j].y);
                acc[j].x = fmaf(n1, __low2float(q1), acc[j].x);
                acc[j].y = fmaf(n1, __high2float(q1), acc[j].y);
                acc[j].x = fmaf(n2, __low2float(q2), acc[j].x);
                acc[j].y = fmaf(n2, __high2float(q2), acc[j].y);
                acc[j].x = fmaf(n3, __low2float(q3), acc[j].x);
                acc[j].y = fmaf(n3, __high2float(q3), acc[j].y);
            }
            for (; i + 1 < iend; i += 2) {
                int2 r = se[i + sub];
                __half2 q = h2[r.x * 32 + fl];
                float nm = __int_as_float(r.y);
                acc[j].x = fmaf(nm, __low2float(q), acc[j].x);
                acc[j].y = fmaf(nm, __high2float(q), acc[j].y);
            }
            if (i < iend) {  // odd tail: sub0 only
                int2 r = se[i];
                __half2 q = h2[r.x * 32 + fl];
                float nm = (sub == 0) ? __int_as_float(r.y) : 0.f;
                acc[j].x = fmaf(nm, __low2float(q), acc[j].x);
                acc[j].y = fmaf(nm, __high2float(q), acc[j].y);
            }
        }
        __builtin_amdgcn_wave_barrier();
    }

    // combine sub-halves: feature pair fl lives in lanes fl and fl+32
#pragma unroll
    for (int j = 0; j < 8; j++) {
        acc[j].x += __shfl_xor(acc[j].x, 32);
        acc[j].y += __shfl_xor(acc[j].y, 32);
    }

    if (!WEP) {
        // layer 0: out = relu(g + b) fp16, written as half2 by sub0 lanes
        float2 bv = ((const float2*)b)[fl];
        if (sub == 0) {
#pragma unroll
            for (int j = 0; j < 8; j++) {
                float ox = fmaxf(acc[j].x + bv.x, 0.f);
                float oy = fmaxf(acc[j].y + bv.y, 0.f);
                ((__half2*)outp)[(n0w + j) * 32 + fl] = __floats2half2_rn(ox, oy);
            }
        }
        return;
    }

    // write G rows (fp16) from sub0 lanes
    if (sub == 0) {
        __half2* G2 = (__half2*)G;
#pragma unroll
        for (int j = 0; j < 8; j++)
            G2[(wv * 8 + j) * (G_STRIDE / 2) + fl] = __floats2half2_rn(acc[j].x, acc[j].y);
    }
    __syncthreads();

    // ---- MFMA epilogue: O[32x64] = G @ (W_hi + W_lo) + b ----
    int col = lane & 15, quad = lane >> 4;
    int mrow = (wv & 1) * 16;
    int nc0 = (wv >> 1) * 32;

    half8 af[2];
#pragma unroll
    for (int kt = 0; kt < 2; kt++)
        af[kt] = *(const half8*)&G[(mrow + col) * G_STRIDE + kt * 32 + quad * 8];

    // all waves have consumed G (and se); LDS is reusable for output staging
    __syncthreads();

    half8 bf[2][2][2];  // [nt][kt][hi/lo]
#pragma unroll
    for (int nt = 0; nt < 2; nt++) {
#pragma unroll
        for (int kt = 0; kt < 2; kt++) {
#pragma unroll
            for (int j = 0; j < 8; j++) {
                float w = W[(kt * 32 + quad * 8 + j) * 64 + nc0 + nt * 16 + col];
                _Float16 hi = (_Float16)w;
                bf[nt][kt][0][j] = hi;
                bf[nt][kt][1][j] = (_Float16)(w - (float)hi);
            }
        }
    }

    f32x4 c0, c1;
    {
        float b0v = b[nc0 + col], b1v = b[nc0 + 16 + col];
        c0 = (f32x4){b0v, b0v, b0v, b0v};
        c1 = (f32x4){b1v, b1v, b1v, b1v};
    }
#pragma unroll
    for (int kt = 0; kt < 2; kt++) {
        c0 = __builtin_amdgcn_mfma_f32_16x16x32_f16(af[kt], bf[0][kt][0], c0, 0, 0, 0);
        c0 = __builtin_amdgcn_mfma_f32_16x16x32_f16(af[kt], bf[0][kt][1], c0, 0, 0, 0);
        c1 = __builtin_amdgcn_mfma_f32_16x16x32_f16(af[kt], bf[1][kt][0], c1, 0, 0, 0);
        c1 = __builtin_amdgcn_mfma_f32_16x16x32_f16(af[kt], bf[1][kt][1], c1, 0, 0, 0);
    }

    // C/D layout: col = lane&15, row = quad*4 + reg.
    // Stage results in LDS, then store full 128 B rows (coalesced).
    if (!SIG) {
#pragma unroll
        for (int nt = 0; nt < 2; nt++) {
            f32x4 c = nt ? c1 : c0;
#pragma unroll
            for (int r = 0; r < 4; r++) {
                float o = fmaxf(c[r], 0.f);  // relu at producer
                G[(mrow + quad * 4 + r) * G_STRIDE + nc0 + nt * 16 + col] =
                    (_Float16)o;
            }
        }
        __syncthreads();
        // 32 rows x 64 half: 256 threads x one half8 (16 B) each
        {
            int row = t >> 3, seg = t & 7;
            half8 v = *(const half8*)&G[row * G_STRIDE + seg * 8];
            *(half8*)((__half*)outp + (nb + row) * 64 + seg * 8) = v;
        }
    } else {
        // fp32 sigmoid output staged at stride 66 (overlays se+G: 8448 B)
        float* fo = (float*)smem;
#pragma unroll
        for (int nt = 0; nt < 2; nt++) {
            f32x4 c = nt ? c1 : c0;
#pragma unroll
            for (int r = 0; r < 4; r++) {
                float o = 1.0f / (1.0f + expf(-c[r]));
                fo[(mrow + quad * 4 + r) * 66 + nc0 + nt * 16 + col] = o;
            }
        }
        __syncthreads();
        // 32 rows x 64 f32: 512 float4 stores from 256 threads
#pragma unroll
        for (int k = 0; k < 2; k++) {
            int lin = t + k * 256;
            int row = lin >> 4, seg = lin & 15;
            float4 v = *(const float4*)&fo[row * 66 + seg * 4];
            *(float4*)((float*)outp + (nb + row) * 64 + seg * 4) = v;
        }
    }
}

// ---------------- launch ----------------

extern "C" void kernel_launch(void* const* d_in, const int* in_sizes, int n_in,
                              void* d_out, int out_size, void* d_ws, size_t ws_size,
                              hipStream_t stream) {
    const float* x  = (const float*)d_in[0];
    const int*   ei = (const int*)  d_in[1];
    const float* ew = (const float*)d_in[2];
    const float* W0 = (const float*)d_in[3];
    const float* b0 = (const float*)d_in[4];
    const float* Wm = (const float*)d_in[5];
    const float* bm = (const float*)d_in[6];
    const float* Wl = (const float*)d_in[7];
    const float* bl = (const float*)d_in[8];
    float* out = (float*)d_out;

    const int* src = ei;
    const int* dst = ei + N_EDGES;

    char* ws = (char*)d_ws;
    int*    hist   = (int*)  (ws + 0);                // 256 KB (NBUCK*NBLK1*4)
    int*    bbase  = (int*)  (ws + (1u << 18));       // ~1 KB (NBUCK+1 ints)
    float*  dinv   = (float*)(ws + (1u << 20));       // 400 KB
    int*    rowptr = (int*)  (ws + (2u << 20));       // 400 KB + 4
    int2*   brec   = (int2*) (ws + (3u << 20));       // 12.8 MB
    int2*   csr    = (int2*) (ws + (16u << 20));      // 12.8 MB
    __half* htmp   = (__half*)(ws + (29u << 20));     // 12.8 MB
    __half* hA     = (__half*)(ws + (42u << 20));     // 12.8 MB
    __half* hB     = (__half*)(ws + (55u << 20));     // 12.8 MB

    int gR4 = (N_NODES + 3) / 4;              // 25000 (gemm0)
    int gG  = N_NODES / 32;                   // 3125 (gather4: 32 nodes/block)

    const size_t smem0 = 4 * SE_CAP * 8;                          // 4 KB
    const size_t smemW = 4 * SE_CAP * 8 + 32 * G_STRIDE * 2;      // 8.5 KB

    // prelude: bucketed counting sort (LDS atomics only), then per-bucket
    // degree/rowptr and final CSR fill
    hipLaunchKernelGGL(k_hist,    dim3(NBLK1), dim3(1024), 0, stream, dst, hist);
    hipLaunchKernelGGL(k_scan,    dim3(1),     dim3(1024), 0, stream, hist, bbase, rowptr);
    hipLaunchKernelGGL(k_scatter, dim3(NBLK1), dim3(1024), 0, stream, src, dst, ew, hist, brec);
    hipLaunchKernelGGL(k_deg,     dim3(NBUCK_USED), dim3(512), 0, stream, brec, bbase, dinv, rowptr);
    hipLaunchKernelGGL(k_csr,     dim3(NBUCK_USED), dim3(512), 0, stream, brec, bbase, rowptr, dinv, csr);

    // layer 0: x W0 -> fp16 (pre-act), then aggregate +b0, relu at store -> hA
    hipLaunchKernelGGL(k_gemm0,   dim3(gR4), dim3(256), 0, stream, x, W0, htmp);
    hipLaunchKernelGGL((k_gather4<false, false>), dim3(gG), dim3(256), smem0, stream,
                       rowptr, csr, htmp, dinv, (const float*)nullptr, b0, (void*)hA);

    // middle layers 1..6: fused (A h) W + b via MFMA, relu at store, fp16 -> fp16
    __half* hin = hA;
    __half* hout = hB;
    for (int i = 0; i < 6; i++) {
        const float* Wi = Wm + (long)i * 64 * 64;
        const float* bi = bm + (long)i * 64;
        hipLaunchKernelGGL((k_gather4<true, false>), dim3(gG), dim3(256), smemW, stream,
                           rowptr, csr, hin, dinv, Wi, bi, (void*)hout);
        __half* t2 = hin; hin = hout; hout = t2;
    }

    // final layer: fused aggregate + W + bias + sigmoid -> fp32 d_out
    hipLaunchKernelGGL((k_gather4<true, true>), dim3(gG), dim3(256), smemW, stream,
                       rowptr, csr, hin, dinv, Wl, bl, (void*)out);
}

// Round 9
// 505.578 us; speedup vs baseline: 1.1883x; 1.0294x over previous
//
#include <hip/hip_runtime.h>
#include <hip/hip_fp16.h>
#include <math.h>

#define N_NODES 100000
#define N_EDGES 1600000
#define F_IN 15
#define MASK40 ((1ull << 40) - 1)

// bucketed counting-sort CSR build: buckets of 512 nodes (dst>>9)
#define NBLK1 256                           // edge-partition blocks for hist/scatter
#define EPB   (N_EDGES / NBLK1)             // 6250 edges per block (exact)
#define NBUCK 256                           // allocated buckets; used = 196
#define NBUCK_USED ((N_NODES + 511) >> 9)   // 196

typedef _Float16 half8 __attribute__((ext_vector_type(8)));
typedef float f32x4 __attribute__((ext_vector_type(4)));

// ---------------- prelude: sort-based CSR build (no global atomics) ----------

// per-block 256-bin histogram of dst>>9 in LDS; hist[bin*NBLK1 + blk]
__global__ __launch_bounds__(1024) void k_hist(const int* __restrict__ dst,
                                               int* __restrict__ hist) {
    __shared__ int bins[NBUCK];
    int t = threadIdx.x, blk = blockIdx.x;
    if (t < NBUCK) bins[t] = 0;
    __syncthreads();
    int e0 = blk * EPB;
    for (int e = e0 + t; e < e0 + EPB; e += 1024)
        atomicAdd(&bins[dst[e] >> 9], 1);
    __syncthreads();
    if (t < NBUCK) hist[t * NBLK1 + blk] = bins[t];
}

// single-block exclusive scan of hist[65536] in place; also bucketBase[b] =
// scan value at b*NBLK1, bucketBase[NBUCK]=E, rowptr[N]=E.
__global__ __launch_bounds__(1024) void k_scan(int* __restrict__ hist,
                                               int* __restrict__ bucketBase,
                                               int* __restrict__ rowptr) {
    __shared__ int sc[1024];
    int t = threadIdx.x;
    int base = t * 64;
    int vals[64];
    int tot = 0;
#pragma unroll
    for (int k = 0; k < 64; k++) { vals[k] = hist[base + k]; tot += vals[k]; }
    sc[t] = tot;
    __syncthreads();
    for (int off = 1; off < 1024; off <<= 1) {
        int u = (t >= off) ? sc[t - off] : 0;
        __syncthreads();
        sc[t] += u;
        __syncthreads();
    }
    int run = sc[t] - tot;  // exclusive base of this thread's segment
#pragma unroll
    for (int k = 0; k < 64; k++) {
        int idx = base + k;
        if ((idx & (NBLK1 - 1)) == 0) bucketBase[idx / NBLK1] = run;
        int v = vals[k];
        hist[idx] = run;
        run += v;
    }
    if (t == 0) { bucketBase[NBUCK] = N_EDGES; rowptr[N_NODES] = N_EDGES; }
}

// scatter edges into bucket-contiguous record array via LDS cursors.
// record: x = src | (dst&511)<<17  (src<2^17, 9-bit dstlo), y = bits(w)
__global__ __launch_bounds__(1024) void k_scatter(const int* __restrict__ src,
        const int* __restrict__ dst, const float* __restrict__ w,
        const int* __restrict__ hist, int2* __restrict__ brec) {
    __shared__ int cursor[NBUCK];
    int t = threadIdx.x, blk = blockIdx.x;
    if (t < NBUCK) cursor[t] = hist[t * NBLK1 + blk];
    __syncthreads();
    int e0 = blk * EPB;
    for (int e = e0 + t; e < e0 + EPB; e += 1024) {
        int d = dst[e];
        int pos = atomicAdd(&cursor[d >> 9], 1);
        brec[pos] = make_int2(src[e] | ((d & 511) << 17), __float_as_int(w[e]));
    }
}

// per-bucket: packed count/weight-sum per node in LDS (same 24.40 packing as
// the old k_cnt -> identical deg numerics), then dinv + rowptr via LDS scan.
__global__ __launch_bounds__(512) void k_deg(const int2* __restrict__ brec,
        const int* __restrict__ bucketBase, float* __restrict__ dinv,
        int* __restrict__ rowptr) {
    __shared__ unsigned long long packedl[512];
    __shared__ int sc[512];
    int t = threadIdx.x, b = blockIdx.x;
    packedl[t] = 0ull;
    __syncthreads();
    int ebase = bucketBase[b], eend = bucketBase[b + 1];
    for (int e = ebase + t; e < eend; e += 512) {
        int2 r = brec[e];
        int dlo = (r.x >> 17) & 511;
        float wv = __int_as_float(r.y);
        unsigned long long contrib =
            (1ull << 40) + (unsigned long long)((double)wv * 4294967296.0);
        atomicAdd(&packedl[dlo], contrib);
    }
    __syncthreads();
    unsigned long long p = packedl[t];
    int cnt = (int)(p >> 40);
    int n = (b << 9) + t;
    if (n < N_NODES) {
        float deg = 1.0f + (float)((double)(p & MASK40) * 0x1p-32);
        dinv[n] = rsqrtf(deg);
    }
    sc[t] = cnt;
    __syncthreads();
    for (int off = 1; off < 512; off <<= 1) {
        int u = (t >= off) ? sc[t - off] : 0;
        __syncthreads();
        sc[t] += u;
        __syncthreads();
    }
    if (n < N_NODES) rowptr[n] = ebase + sc[t] - cnt;  // exclusive prefix
}

// per-bucket final CSR fill: LDS cursors seeded from rowptr; nm in fp32 with
// the exact formula the old k_fill used. csr[].x stores src PRE-SCALED to a
// byte offset (src*128) so the gather's per-load address math is one v_add.
__global__ __launch_bounds__(512) void k_csr(const int2* __restrict__ brec,
        const int* __restrict__ bucketBase, const int* __restrict__ rowptr,
        const float* __restrict__ dinv, int2* __restrict__ csr) {
    __shared__ int cursor[512];
    __shared__ float dl[512];
    int t = threadIdx.x, b = blockIdx.x;
    int n = (b << 9) + t;
    if (n < N_NODES) { cursor[t] = rowptr[n]; dl[t] = dinv[n]; }
    else             { cursor[t] = 0;         dl[t] = 0.f; }
    __syncthreads();
    int ebase = bucketBase[b], eend = bucketBase[b + 1];
    for (int e = ebase + t; e < eend; e += 512) {
        int2 r = brec[e];
        int dlo = (r.x >> 17) & 511;
        int s = r.x & 0x1FFFF;
        float wv = __int_as_float(r.y);
        int slot = atomicAdd(&cursor[dlo], 1);
        float nm = dinv[s] * wv * dl[dlo];
        csr[slot] = make_int2(s << 7, __float_as_int(nm));   // byte offset of row
    }
}

// ---------------- layer 0 dense transform: [N,15]@[15,64] -> fp16 (no relu) ----

__global__ void k_gemm0(const float* __restrict__ x, const float* __restrict__ W,
                        __half* __restrict__ out) {
    __shared__ float Ws[F_IN * 64];
    int t = threadIdx.x;
    for (int i = t; i < F_IN * 64; i += 256) Ws[i] = W[i];
    __syncthreads();
    int r = blockIdx.x * 4 + (t >> 6);
    int c = t & 63;
    if (r < N_NODES) {
        const float* xr = x + r * F_IN;      // int index: < 1.5M
        float acc = 0.f;
#pragma unroll
        for (int k = 0; k < F_IN; k++) acc += xr[k] * Ws[k * 64 + c];
        out[r * 64 + c] = __float2half(acc); // int index: < 6.4M
    }
}

// ---------------- fused aggregation + MFMA dense epilogue ----------------
// Wave = 8 nodes; lane = (sub: which edge of a pair) x (fl: feature pair).
// Edge records staged in LDS. csr[].x is the PRE-SCALED byte offset of the
// source row (src*128), so each gather load is one v_add_u32 (+ hoisted
// fl*4) + saddr global_load_dword -- no per-load shift/mad chain.
// 8-edge unroll (R6 shape; 16-edge spilled). Outputs staged in LDS and
// stored as full 128 B rows (half8 / float4).

#define SE_CAP 128          // staged edges per wave (chunked if exceeded)
#define G_STRIDE 72         // halves; 144 B rows keep half8 loads 16B-aligned

template <bool WEP, bool SIG>
__global__ __launch_bounds__(256, 8) void k_gather4(
        const int* __restrict__ rowptr, const int2* __restrict__ csr,
        const __half* __restrict__ hin, const float* __restrict__ dinv,
        const float* __restrict__ W, const float* __restrict__ b,
        void* __restrict__ outp) {
    extern __shared__ char smem[];
    int t = threadIdx.x, wv = t >> 6, lane = t & 63;
    int sub = lane >> 5, fl = lane & 31;
    int2* se = (int2*)smem + wv * SE_CAP;                 // 4 x 1 KB
    _Float16* G = (_Float16*)(smem + 4 * SE_CAP * 8);     // [32][G_STRIDE]

    int nb = blockIdx.x * 32;      // grid exact: 3125*32 = 100000
    int n0w = nb + wv * 8;

    int rp[9];
#pragma unroll
    for (int j = 0; j < 9; j++) rp[j] = rowptr[n0w + j];
    int base = rp[0], end = rp[8];

    const char* hb = (const char*)hin;   // rows of 128 B
    unsigned flb = (unsigned)fl * 4u;    // this lane's byte offset within a row

    // self-loop init: acc[j] = dinv^2 * h (h already activated by producer)
    const __half2* h2 = (const __half2*)hin;  // row stride = 32 half2
    float2 acc[8];
#pragma unroll
    for (int j = 0; j < 8; j++) {
        int n = n0w + j;
        float dv = dinv[n];
        __half2 hq = h2[n * 32 + fl];
        float w0 = (sub == 0) ? dv * dv : 0.f;
        acc[j].x = w0 * __low2float(hq);
        acc[j].y = w0 * __high2float(hq);
    }

    for (int cb = base; cb < end; cb += SE_CAP) {
        int ce = cb + SE_CAP; if (ce > end) ce = end;
        int cn = ce - cb;
        for (int i = lane; i < cn; i += 64) se[i] = csr[cb + i];
        __builtin_amdgcn_wave_barrier();
#pragma unroll
        for (int j = 0; j < 8; j++) {
            int lo = rp[j] < cb ? cb : rp[j];
            int hi = rp[j + 1] > ce ? ce : rp[j + 1];
            int i = lo - cb, iend = hi - cb;
            // 4 pairs (8 edges) per iteration
            for (; i + 7 < iend; i += 8) {
                int2 r0 = se[i + sub],     r1 = se[i + 2 + sub];
                int2 r2 = se[i + 4 + sub], r3 = se[i + 6 + sub];
                __half2 q0 = *(const __half2*)(hb + (size_t)((unsigned)r0.x + flb));
                __half2 q1 = *(const __half2*)(hb + (size_t)((unsigned)r1.x + flb));
                __half2 q2 = *(const __half2*)(hb + (size_t)((unsigned)r2.x + flb));
                __half2 q3 = *(const __half2*)(hb + (size_t)((unsigned)r3.x + flb));
                float n0 = __int_as_float(r0.y), n1 = __int_as_float(r1.y);
                float n2 = __int_as_float(r2.y), n3 = __int_as_float(r3.y);
                acc[j].x = fmaf(n0, __low2float(q0), acc[j].x);
                acc[j].y = fmaf(n0, __high2float(q0), acc[j].y);
                acc[j].x = fmaf(n1, __low2float(q1), acc[j].x);
                acc[j].y = fmaf(n1, __high2float(q1), acc[j].y);
                acc[j].x = fmaf(n2, __low2float(q2), acc[j].x);
                acc[j].y = fmaf(n2, __high2float(q2), acc[j].y);
                acc[j].x = fmaf(n3, __low2float(q3), acc[j].x);
                acc[j].y = fmaf(n3, __high2float(q3), acc[j].y);
            }
            for (; i + 1 < iend; i += 2) {
                int2 r = se[i + sub];
                __half2 q = *(const __half2*)(hb + (size_t)((unsigned)r.x + flb));
                float nm = __int_as_float(r.y);
                acc[j].x = fmaf(nm, __low2float(q), acc[j].x);
                acc[j].y = fmaf(nm, __high2float(q), acc[j].y);
            }
            if (i < iend) {  // odd tail: sub0 only
                int2 r = se[i];
                __half2 q = *(const __half2*)(hb + (size_t)((unsigned)r.x + flb));
                float nm = (sub == 0) ? __int_as_float(r.y) : 0.f;
                acc[j].x = fmaf(nm, __low2float(q), acc[j].x);
                acc[j].y = fmaf(nm, __high2float(q), acc[j].y);
            }
        }
        __builtin_amdgcn_wave_barrier();
    }

    // combine sub-halves: feature pair fl lives in lanes fl and fl+32
#pragma unroll
    for (int j = 0; j < 8; j++) {
        acc[j].x += __shfl_xor(acc[j].x, 32);
        acc[j].y += __shfl_xor(acc[j].y, 32);
    }

    if (!WEP) {
        // layer 0: out = relu(g + b) fp16, written as half2 by sub0 lanes
        float2 bv = ((const float2*)b)[fl];
        if (sub == 0) {
#pragma unroll
            for (int j = 0; j < 8; j++) {
                float ox = fmaxf(acc[j].x + bv.x, 0.f);
                float oy = fmaxf(acc[j].y + bv.y, 0.f);
                ((__half2*)outp)[(n0w + j) * 32 + fl] = __floats2half2_rn(ox, oy);
            }
        }
        return;
    }

    // write G rows (fp16) from sub0 lanes
    if (sub == 0) {
        __half2* G2 = (__half2*)G;
#pragma unroll
        for (int j = 0; j < 8; j++)
            G2[(wv * 8 + j) * (G_STRIDE / 2) + fl] = __floats2half2_rn(acc[j].x, acc[j].y);
    }
    __syncthreads();

    // ---- MFMA epilogue: O[32x64] = G @ (W_hi + W_lo) + b ----
    int col = lane & 15, quad = lane >> 4;
    int mrow = (wv & 1) * 16;
    int nc0 = (wv >> 1) * 32;

    half8 af[2];
#pragma unroll
    for (int kt = 0; kt < 2; kt++)
        af[kt] = *(const half8*)&G[(mrow + col) * G_STRIDE + kt * 32 + quad * 8];

    // all waves have consumed G (and se); LDS is reusable for output staging
    __syncthreads();

    half8 bf[2][2][2];  // [nt][kt][hi/lo]
#pragma unroll
    for (int nt = 0; nt < 2; nt++) {
#pragma unroll
        for (int kt = 0; kt < 2; kt++) {
#pragma unroll
            for (int j = 0; j < 8; j++) {
                float w = W[(kt * 32 + quad * 8 + j) * 64 + nc0 + nt * 16 + col];
                _Float16 hi = (_Float16)w;
                bf[nt][kt][0][j] = hi;
                bf[nt][kt][1][j] = (_Float16)(w - (float)hi);
            }
        }
    }

    f32x4 c0, c1;
    {
        float b0v = b[nc0 + col], b1v = b[nc0 + 16 + col];
        c0 = (f32x4){b0v, b0v, b0v, b0v};
        c1 = (f32x4){b1v, b1v, b1v, b1v};
    }
#pragma unroll
    for (int kt = 0; kt < 2; kt++) {
        c0 = __builtin_amdgcn_mfma_f32_16x16x32_f16(af[kt], bf[0][kt][0], c0, 0, 0, 0);
        c0 = __builtin_amdgcn_mfma_f32_16x16x32_f16(af[kt], bf[0][kt][1], c0, 0, 0, 0);
        c1 = __builtin_amdgcn_mfma_f32_16x16x32_f16(af[kt], bf[1][kt][0], c1, 0, 0, 0);
        c1 = __builtin_amdgcn_mfma_f32_16x16x32_f16(af[kt], bf[1][kt][1], c1, 0, 0, 0);
    }

    // C/D layout: col = lane&15, row = quad*4 + reg.
    // Stage results in LDS, then store full 128 B rows (coalesced).
    if (!SIG) {
#pragma unroll
        for (int nt = 0; nt < 2; nt++) {
            f32x4 c = nt ? c1 : c0;
#pragma unroll
            for (int r = 0; r < 4; r++) {
                float o = fmaxf(c[r], 0.f);  // relu at producer
                G[(mrow + quad * 4 + r) * G_STRIDE + nc0 + nt * 16 + col] =
                    (_Float16)o;
            }
        }
        __syncthreads();
        // 32 rows x 64 half: 256 threads x one half8 (16 B) each
        {
            int row = t >> 3, seg = t & 7;
            half8 v = *(const half8*)&G[row * G_STRIDE + seg * 8];
            *(half8*)((__half*)outp + (nb + row) * 64 + seg * 8) = v;
        }
    } else {
        // fp32 sigmoid output staged at stride 66 (overlays se+G: 8448 B)
        float* fo = (float*)smem;
#pragma unroll
        for (int nt = 0; nt < 2; nt++) {
            f32x4 c = nt ? c1 : c0;
#pragma unroll
            for (int r = 0; r < 4; r++) {
                float o = 1.0f / (1.0f + expf(-c[r]));
                fo[(mrow + quad * 4 + r) * 66 + nc0 + nt * 16 + col] = o;
            }
        }
        __syncthreads();
        // 32 rows x 64 f32: 512 float4 stores from 256 threads
#pragma unroll
        for (int k = 0; k < 2; k++) {
            int lin = t + k * 256;
            int row = lin >> 4, seg = lin & 15;
            float4 v = *(const float4*)&fo[row * 66 + seg * 4];
            *(float4*)((float*)outp + (nb + row) * 64 + seg * 4) = v;
        }
    }
}

// ---------------- launch ----------------

extern "C" void kernel_launch(void* const* d_in, const int* in_sizes, int n_in,
                              void* d_out, int out_size, void* d_ws, size_t ws_size,
                              hipStream_t stream) {
    const float* x  = (const float*)d_in[0];
    const int*   ei = (const int*)  d_in[1];
    const float* ew = (const float*)d_in[2];
    const float* W0 = (const float*)d_in[3];
    const float* b0 = (const float*)d_in[4];
    const float* Wm = (const float*)d_in[5];
    const float* bm = (const float*)d_in[6];
    const float* Wl = (const float*)d_in[7];
    const float* bl = (const float*)d_in[8];
    float* out = (float*)d_out;

    const int* src = ei;
    const int* dst = ei + N_EDGES;

    char* ws = (char*)d_ws;
    int*    hist   = (int*)  (ws + 0);                // 256 KB (NBUCK*NBLK1*4)
    int*    bbase  = (int*)  (ws + (1u << 18));       // ~1 KB (NBUCK+1 ints)
    float*  dinv   = (float*)(ws + (1u << 20));       // 400 KB
    int*    rowptr = (int*)  (ws + (2u << 20));       // 400 KB + 4
    int2*   brec   = (int2*) (ws + (3u << 20));       // 12.8 MB
    int2*   csr    = (int2*) (ws + (16u << 20));      // 12.8 MB
    __half* htmp   = (__half*)(ws + (29u << 20));     // 12.8 MB
    __half* hA     = (__half*)(ws + (42u << 20));     // 12.8 MB
    __half* hB     = (__half*)(ws + (55u << 20));     // 12.8 MB

    int gR4 = (N_NODES + 3) / 4;              // 25000 (gemm0)
    int gG  = N_NODES / 32;                   // 3125 (gather4: 32 nodes/block)

    const size_t smem0 = 4 * SE_CAP * 8;                          // 4 KB
    const size_t smemW = 4 * SE_CAP * 8 + 32 * G_STRIDE * 2;      // 8.5 KB

    // prelude: bucketed counting sort (LDS atomics only), then per-bucket
    // degree/rowptr and final CSR fill
    hipLaunchKernelGGL(k_hist,    dim3(NBLK1), dim3(1024), 0, stream, dst, hist);
    hipLaunchKernelGGL(k_scan,    dim3(1),     dim3(1024), 0, stream, hist, bbase, rowptr);
    hipLaunchKernelGGL(k_scatter, dim3(NBLK1), dim3(1024), 0, stream, src, dst, ew, hist, brec);
    hipLaunchKernelGGL(k_deg,     dim3(NBUCK_USED), dim3(512), 0, stream, brec, bbase, dinv, rowptr);
    hipLaunchKernelGGL(k_csr,     dim3(NBUCK_USED), dim3(512), 0, stream, brec, bbase, rowptr, dinv, csr);

    // layer 0: x W0 -> fp16 (pre-act), then aggregate +b0, relu at store -> hA
    hipLaunchKernelGGL(k_gemm0,   dim3(gR4), dim3(256), 0, stream, x, W0, htmp);
    hipLaunchKernelGGL((k_gather4<false, false>), dim3(gG), dim3(256), smem0, stream,
                       rowptr, csr, htmp, dinv, (const float*)nullptr, b0, (void*)hA);

    // middle layers 1..6: fused (A h) W + b via MFMA, relu at store, fp16 -> fp16
    __half* hin = hA;
    __half* hout = hB;
    for (int i = 0; i < 6; i++) {
        const float* Wi = Wm + (long)i * 64 * 64;
        const float* bi = bm + (long)i * 64;
        hipLaunchKernelGGL((k_gather4<true, false>), dim3(gG), dim3(256), smemW, stream,
                           rowptr, csr, hin, dinv, Wi, bi, (void*)hout);
        __half* t2 = hin; hin = hout; hout = t2;
    }

    // final layer: fused aggregate + W + bias + sigmoid -> fp32 d_out
    hipLaunchKernelGGL((k_gather4<true, true>), dim3(gG), dim3(256), smemW, stream,
                       rowptr, csr, hin, dinv, Wl, bl, (void*)out);
}